// Round 2
// baseline (1137.521 us; speedup 1.0000x reference)
//
#include <hip/hip_runtime.h>
#include <math.h>

#define NROWS 65536
#define DD 64
#define RR 256
#define ZTOT (RR*DD + RR)   // 16640 floats: z[256][64] then ksum[256]

// sc = 64^{-1/4} = 2^{-1.5}
#define SC 0.35355339059327373f
// ln(1/16)
#define LNRATIO -2.772588722239781f

// ---------------- Kernel A: phi(k)^T @ v and sum(phi(k)) partials ----------------
// 512 threads. Lane pair (2r, 2r+1) owns projection row r; parity p owns half
// of the d-dim and half of the v columns. Per-lane state: Preg[32]+zacc[32].
__global__ __launch_bounds__(512, 4)
void favor_kv_kernel(const float* __restrict__ k,
                     const float* __restrict__ v,
                     const float* __restrict__ P,
                     float* __restrict__ partials,   // [nblk][ZTOT]
                     int rowsPerBlock)
{
    const int t = threadIdx.x;
    const int r = t >> 1;          // projection row 0..255
    const int p = t & 1;           // half index
    const int b = blockIdx.x;

    // Preload scaled half projection row (sc folded in)
    float Preg[32];
    {
        const float4* Pr4 = (const float4*)(P + r * 64 + p * 32);
        #pragma unroll
        for (int j = 0; j < 8; j++) {
            float4 pv = Pr4[j];
            Preg[4*j+0] = SC * pv.x; Preg[4*j+1] = SC * pv.y;
            Preg[4*j+2] = SC * pv.z; Preg[4*j+3] = SC * pv.w;
        }
    }

    float zacc[32];
    #pragma unroll
    for (int c = 0; c < 32; c++) zacc[c] = 0.0f;
    float ksum = 0.0f;

    __shared__ float rowconst[128];

    int row0 = b * rowsPerBlock;
    int row1 = row0 + rowsPerBlock;
    if (row1 > NROWS) row1 = NROWS;

    for (int tile = row0; tile < row1; tile += 128) {
        int tn = row1 - tile;
        if (tn > 128) tn = 128;

        // per-row constant  -0.5*||sc*k_row||^2 + ln(ratio)
        if (t < tn) {
            const float4* kr = (const float4*)(k + (size_t)(tile + t) * 64);
            float s0 = 0.f, s1 = 0.f;
            #pragma unroll
            for (int j = 0; j < 16; j += 2) {
                float4 a = kr[j];     s0 += a.x*a.x + a.y*a.y + a.z*a.z + a.w*a.w;
                float4 bq = kr[j+1];  s1 += bq.x*bq.x + bq.y*bq.y + bq.z*bq.z + bq.w*bq.w;
            }
            rowconst[t] = -0.5f * SC * SC * (s0 + s1) + LNRATIO;
        }
        __syncthreads();

        for (int i = 0; i < tn; i++) {
            const float4* kr4 = (const float4*)(k + (size_t)(tile + i) * 64 + p * 32);
            float d0 = 0.f, d1 = 0.f, d2 = 0.f, d3 = 0.f;
            #pragma unroll
            for (int j = 0; j < 8; j += 4) {
                float4 a = kr4[j];
                d0 += a.x * Preg[4*j+0]; d1 += a.y * Preg[4*j+1];
                d2 += a.z * Preg[4*j+2]; d3 += a.w * Preg[4*j+3];
                float4 bq = kr4[j+1];
                d0 += bq.x * Preg[4*j+4]; d1 += bq.y * Preg[4*j+5];
                d2 += bq.z * Preg[4*j+6]; d3 += bq.w * Preg[4*j+7];
                float4 cq = kr4[j+2];
                d0 += cq.x * Preg[4*j+8]; d1 += cq.y * Preg[4*j+9];
                d2 += cq.z * Preg[4*j+10]; d3 += cq.w * Preg[4*j+11];
                float4 dq = kr4[j+3];
                d0 += dq.x * Preg[4*j+12]; d1 += dq.y * Preg[4*j+13];
                d2 += dq.z * Preg[4*j+14]; d3 += dq.w * Preg[4*j+15];
            }
            float d = (d0 + d1) + (d2 + d3);
            d += __shfl_xor(d, 1);           // combine the two halves of the dot
            float phi = __expf(d + rowconst[i]);
            ksum += phi;
            const float4* vr4 = (const float4*)(v + (size_t)(tile + i) * 64 + p * 32);
            #pragma unroll
            for (int j = 0; j < 8; j++) {
                float4 vv = vr4[j];
                zacc[4*j+0] += phi * vv.x; zacc[4*j+1] += phi * vv.y;
                zacc[4*j+2] += phi * vv.z; zacc[4*j+3] += phi * vv.w;
            }
        }
        __syncthreads();
    }

    // Write this block's partial slot (fully written; no zero-init needed)
    float* slot = partials + (size_t)b * ZTOT;
    #pragma unroll
    for (int j = 0; j < 8; j++) {
        *(float4*)(slot + r * 64 + p * 32 + 4*j) =
            make_float4(zacc[4*j+0], zacc[4*j+1], zacc[4*j+2], zacc[4*j+3]);
    }
    if (p == 0) slot[RR * DD + r] = ksum;
}

// ---------------- Reduce: sum partials -> final z + ksum ----------------
__global__ __launch_bounds__(256)
void favor_reduce_kernel(const float* __restrict__ partials,
                         float* __restrict__ zfinal,
                         int nblk)
{
    int idx = blockIdx.x * 256 + threadIdx.x;   // 65*256 == 16640 exactly
    float s = 0.0f;
    for (int b = 0; b < nblk; b++) s += partials[(size_t)b * ZTOT + idx];
    zfinal[idx] = s;
}

// ---------------- Kernel B: out = diag(1/(phi(q)·ksum)) * phi(q) @ z ----------------
// 512 threads. rh = r-half (0: r<128, 1: r>=128). Within a half, lane pair owns
// one q row; parity p owns half the d-dim and half the output columns.
__global__ __launch_bounds__(512, 4)
void favor_out_kernel(const float* __restrict__ q,
                      const float* __restrict__ P,
                      const float* __restrict__ zf,    // z[256*64] then ksum[256]
                      float* __restrict__ out)
{
    const int t = threadIdx.x;
    const int rh = t >> 8;          // which r-half this thread processes
    const int tl = t & 255;
    const int p = tl & 1;
    const int il = tl >> 1;         // local row 0..127
    const int row = blockIdx.x * 128 + il;

    // Load scaled half q row, compute row constant via pair shuffle
    float qreg[32];
    float s0 = 0.f, s1 = 0.f;
    {
        const float4* qr4 = (const float4*)(q + (size_t)row * 64 + p * 32);
        #pragma unroll
        for (int j = 0; j < 8; j += 2) {
            float4 a = qr4[j];
            qreg[4*j+0] = SC*a.x; qreg[4*j+1] = SC*a.y; qreg[4*j+2] = SC*a.z; qreg[4*j+3] = SC*a.w;
            s0 += qreg[4*j+0]*qreg[4*j+0] + qreg[4*j+1]*qreg[4*j+1]
                + qreg[4*j+2]*qreg[4*j+2] + qreg[4*j+3]*qreg[4*j+3];
            float4 bq = qr4[j+1];
            qreg[4*j+4] = SC*bq.x; qreg[4*j+5] = SC*bq.y; qreg[4*j+6] = SC*bq.z; qreg[4*j+7] = SC*bq.w;
            s1 += qreg[4*j+4]*qreg[4*j+4] + qreg[4*j+5]*qreg[4*j+5]
                + qreg[4*j+6]*qreg[4*j+6] + qreg[4*j+7]*qreg[4*j+7];
        }
    }
    float nrm = s0 + s1;
    nrm += __shfl_xor(nrm, 1);
    const float cst = -0.5f * nrm + LNRATIO;

    float w[32];
    #pragma unroll
    for (int c = 0; c < 32; c++) w[c] = 0.0f;
    float denom = 0.0f;

    const float* ks = zf + RR * DD;
    const int r0 = rh * 128;
    for (int r = r0; r < r0 + 128; r++) {
        const float4* Pr4 = (const float4*)(P + r * 64 + p * 32);
        float d0 = 0.f, d1 = 0.f, d2 = 0.f, d3 = 0.f;
        #pragma unroll
        for (int j = 0; j < 8; j++) {
            float4 a = Pr4[j];
            d0 += a.x * qreg[4*j+0]; d1 += a.y * qreg[4*j+1];
            d2 += a.z * qreg[4*j+2]; d3 += a.w * qreg[4*j+3];
        }
        float d = (d0 + d1) + (d2 + d3);
        d += __shfl_xor(d, 1);
        float phi = __expf(d + cst);
        denom += phi * ks[r];
        const float4* zr4 = (const float4*)(zf + r * 64 + p * 32);
        #pragma unroll
        for (int j = 0; j < 8; j++) {
            float4 zv = zr4[j];
            w[4*j+0] += phi * zv.x; w[4*j+1] += phi * zv.y;
            w[4*j+2] += phi * zv.z; w[4*j+3] += phi * zv.w;
        }
    }

    // Combine the two r-halves through LDS (transposed layout: 2-way = free)
    __shared__ float wsh[32 * 256];
    __shared__ float dsh[256];
    if (rh) {
        #pragma unroll
        for (int c = 0; c < 32; c++) wsh[c * 256 + tl] = w[c];
        dsh[tl] = denom;
    }
    __syncthreads();
    if (!rh) {
        denom += dsh[tl];
        #pragma unroll
        for (int c = 0; c < 32; c++) w[c] += wsh[c * 256 + tl];
        float inv = 1.0f / denom;
        #pragma unroll
        for (int j = 0; j < 8; j++) {
            *(float4*)(out + (size_t)row * 64 + p * 32 + 4*j) =
                make_float4(w[4*j+0]*inv, w[4*j+1]*inv, w[4*j+2]*inv, w[4*j+3]*inv);
        }
    }
}

extern "C" void kernel_launch(void* const* d_in, const int* in_sizes, int n_in,
                              void* d_out, int out_size, void* d_ws, size_t ws_size,
                              hipStream_t stream) {
    const float* q = (const float*)d_in[0];
    const float* k = (const float*)d_in[1];
    const float* v = (const float*)d_in[2];
    const float* P = (const float*)d_in[3];
    float* out = (float*)d_out;

    float* zfinal = (float*)d_ws;            // ZTOT floats
    float* partials = zfinal + ZTOT;

    long availFloats = (long)(ws_size / 4);
    long slots = (availFloats - (long)ZTOT) / (long)ZTOT;
    int nblk = (int)(slots < 512 ? slots : 512);
    if (nblk < 1) nblk = 1;
    int rpb = (NROWS + nblk - 1) / nblk;

    favor_kv_kernel<<<nblk, 512, 0, stream>>>(k, v, P, partials, rpb);
    favor_reduce_kernel<<<65, 256, 0, stream>>>(partials, zfinal, nblk);
    favor_out_kernel<<<512, 512, 0, stream>>>(q, P, zfinal, out);
}

// Round 3
// 247.132 us; speedup vs baseline: 4.6029x; 4.6029x over previous
//
#include <hip/hip_runtime.h>
#include <math.h>

typedef __attribute__((ext_vector_type(8))) short bf16x8;
typedef __attribute__((ext_vector_type(4))) float f32x4;

#define NROWS 65536
#define RFEAT 256
#define DDIM 64
#define NCOL 80                         // 64 v-cols + ksum col(64) + 15 pad
#define PARTN (RFEAT * NCOL)            // 20480 floats per partial slot

// sc = 64^{-1/4} = 2^{-1.5}; ln(ratio) = ln(1/16)
#define SC 0.35355339059327373f
#define LNRATIO -2.772588722239781f

__device__ __forceinline__ unsigned short f2bf(float f) {
    union { float f; unsigned int u; } v; v.f = f;
    unsigned int r = v.u + 0x7FFFu + ((v.u >> 16) & 1u);   // RNE
    return (unsigned short)(r >> 16);
}

// ---------------- K0: P -> bf16 B-fragment layout (sc folded in) ----------------
// Pb holds 32 frags (kstep 0..1 x ntile 0..15); frag f, lane l at ushort idx f*512 + l*8.
// Frag element j = B[k][n] = sc*P[n][k], n = nt*16 + (l&15), k = kstep*32 + (l>>4)*8 + j.
__global__ void prep_pb_kernel(const float* __restrict__ P, unsigned short* __restrict__ Pb)
{
    const int t = threadIdx.x, l = t & 63, g = t >> 6;
    for (int f = g * 8; f < g * 8 + 8; f++) {
        const int kstep = f >> 4, nt = f & 15;
        const float* src = P + (nt * 16 + (l & 15)) * 64 + kstep * 32 + (l >> 4) * 8;
        bf16x8 frag;
        #pragma unroll
        for (int j = 0; j < 8; j++) frag[j] = (short)f2bf(SC * src[j]);
        *(bf16x8*)(Pb + f * 512 + l * 8) = frag;
    }
}

// ---------------- phi of a 64-row chunk -> LDS (bf16), via MFMA ----------------
// TRANS=true : phi_lds[col*LDP + row]  (A-frags along k-rows, for kv kernel)
// TRANS=false: phi_lds[row*LDP + col]  (A-frags along features, for q kernel)
template<int LDP, bool TRANS>
__device__ __forceinline__ void phi_chunk(const float* __restrict__ X, int chunkBase,
                                          const unsigned short* __restrict__ Pb,
                                          unsigned short* phi_lds, float* rc)
{
    const int t = threadIdx.x, l = t & 63, w = t >> 6;
    if (t < 64) {   // per-row constant: -0.5*sc^2*||x||^2 + ln(ratio)
        const float4* xr = (const float4*)(X + (size_t)(chunkBase + t) * 64);
        float s0 = 0.f, s1 = 0.f;
        #pragma unroll
        for (int j = 0; j < 16; j += 2) {
            float4 a = xr[j];     s0 += a.x*a.x + a.y*a.y + a.z*a.z + a.w*a.w;
            float4 b = xr[j + 1]; s1 += b.x*b.x + b.y*b.y + b.z*b.z + b.w*b.w;
        }
        rc[t] = -0.5f * (SC * SC) * (s0 + s1) + LNRATIO;
    }
    // A-frags: wave w owns rows [chunkBase+16w, +16); m = l&15, k = (l>>4)*8 + j (+32 for kstep 1)
    const float* ar = X + (size_t)(chunkBase + 16 * w + (l & 15)) * 64 + (l >> 4) * 8;
    bf16x8 a0, a1;
    #pragma unroll
    for (int j = 0; j < 8; j++) a0[j] = (short)f2bf(ar[j]);
    #pragma unroll
    for (int j = 0; j < 8; j++) a1[j] = (short)f2bf(ar[32 + j]);
    __syncthreads();   // rc ready; also: all threads finished reading previous chunk's phi_lds
    #pragma unroll
    for (int nt = 0; nt < 16; nt++) {
        bf16x8 b0 = *(const bf16x8*)(Pb + nt * 512 + l * 8);
        bf16x8 b1 = *(const bf16x8*)(Pb + (16 + nt) * 512 + l * 8);
        f32x4 acc = (f32x4){0.f, 0.f, 0.f, 0.f};
        acc = __builtin_amdgcn_mfma_f32_16x16x32_bf16(a0, b0, acc, 0, 0, 0);
        acc = __builtin_amdgcn_mfma_f32_16x16x32_bf16(a1, b1, acc, 0, 0, 0);
        const int col = nt * 16 + (l & 15);
        #pragma unroll
        for (int reg = 0; reg < 4; reg++) {
            const int rloc = 16 * w + (l >> 4) * 4 + reg;   // D: row=(l>>4)*4+reg, col=l&15
            float phi = __expf(acc[reg] + rc[rloc]);
            if (TRANS) phi_lds[col * LDP + rloc] = f2bf(phi);
            else       phi_lds[rloc * LDP + col] = f2bf(phi);
        }
    }
    __syncthreads();
}

// ---------------- kv_fused: partials = phi(K)^T @ [V | 1] over this block's rows ----------------
__global__ __launch_bounds__(256, 2)
void kv_fused_kernel(const float* __restrict__ Kp, const float* __restrict__ V,
                     const unsigned short* __restrict__ Pb,
                     float* __restrict__ partials, int chunksPerBlock)
{
    __shared__ unsigned short phi_lds[RFEAT * 72];   // [feat][krow], padded
    __shared__ float rc[64];
    const int t = threadIdx.x, l = t & 63, w = t >> 6;

    f32x4 acc[4][5];
    #pragma unroll
    for (int mt = 0; mt < 4; mt++)
        #pragma unroll
        for (int nt = 0; nt < 5; nt++) acc[mt][nt] = (f32x4){0.f, 0.f, 0.f, 0.f};

    bf16x8 ones;   // B-frag for ksum column: B[k][64]=1, rest 0 -> lanes with (l&15)==0
    #pragma unroll
    for (int j = 0; j < 8; j++) ones[j] = (short)(((l & 15) == 0) ? 0x3F80 : 0);

    const int base = blockIdx.x * chunksPerBlock * 64;
    for (int c = 0; c < chunksPerBlock; c++) {
        const int cb = base + c * 64;
        phi_chunk<72, true>(Kp, cb, Pb, phi_lds, rc);
        #pragma unroll
        for (int ks = 0; ks < 2; ks++) {
            bf16x8 af[4];   // A = phi(K)^T: m=feature, k=krow; wave w owns feats [64w,+64)
            #pragma unroll
            for (int mt = 0; mt < 4; mt++)
                af[mt] = *(const bf16x8*)(phi_lds + (64 * w + mt * 16 + (l & 15)) * 72
                                          + ks * 32 + (l >> 4) * 8);
            const int krow = cb + ks * 32 + (l >> 4) * 8;
            bf16x8 bf4[4];  // B = V[k][n]: n = nt*16 + (l&15), k along j (row-strided)
            #pragma unroll
            for (int nt = 0; nt < 4; nt++) {
                const float* vp = V + (size_t)krow * 64 + nt * 16 + (l & 15);
                bf16x8 bb;
                #pragma unroll
                for (int j = 0; j < 8; j++) bb[j] = (short)f2bf(vp[j * 64]);
                bf4[nt] = bb;
            }
            #pragma unroll
            for (int mt = 0; mt < 4; mt++) {
                #pragma unroll
                for (int nt = 0; nt < 4; nt++)
                    acc[mt][nt] = __builtin_amdgcn_mfma_f32_16x16x32_bf16(af[mt], bf4[nt], acc[mt][nt], 0, 0, 0);
                acc[mt][4] = __builtin_amdgcn_mfma_f32_16x16x32_bf16(af[mt], ones, acc[mt][4], 0, 0, 0);
            }
        }
    }
    float* slot = partials + (size_t)blockIdx.x * PARTN;
    #pragma unroll
    for (int mt = 0; mt < 4; mt++)
        #pragma unroll
        for (int nt = 0; nt < 5; nt++)
            #pragma unroll
            for (int reg = 0; reg < 4; reg++)
                slot[(64 * w + mt * 16 + (l >> 4) * 4 + reg) * 80 + nt * 16 + (l & 15)] = acc[mt][nt][reg];
}

// ---------------- reduce: sum partials -> Zb (bf16, B-frag octet layout) ----------------
// Zb element (m,n) at ushort ((m>>3)*80 + n)*8 + (m&7); col 64 = ksum.
__global__ __launch_bounds__(256)
void reduce_kernel(const float* __restrict__ partials, unsigned short* __restrict__ Zb, int nslots)
{
    const int idx = blockIdx.x * 256 + threadIdx.x;   // 80*256 == 20480 exactly
    float s = 0.f;
    for (int b = 0; b < nslots; b++) s += partials[(size_t)b * PARTN + idx];
    const int m = idx / 80, n = idx - m * 80;
    Zb[((m >> 3) * 80 + n) * 8 + (m & 7)] = f2bf(s);
}

// ---------------- q_out: out = normalize( phi(Q) @ Zb ) ----------------
__global__ __launch_bounds__(256, 2)
void q_out_kernel(const float* __restrict__ Q, const unsigned short* __restrict__ Pb,
                  const unsigned short* __restrict__ Zb, float* __restrict__ out)
{
    __shared__ unsigned short phi_lds[64 * 272];   // [row][feat], padded (544B rows, 16B-aligned)
    __shared__ float rc[64];
    const int t = threadIdx.x, l = t & 63, w = t >> 6;
    const int base = blockIdx.x * 64;

    phi_chunk<272, false>(Q, base, Pb, phi_lds, rc);

    f32x4 acc[5];
    #pragma unroll
    for (int nt = 0; nt < 5; nt++) acc[nt] = (f32x4){0.f, 0.f, 0.f, 0.f};

    #pragma unroll
    for (int ks = 0; ks < 8; ks++) {
        // A = phi(Q): m = qrow (wave w rows 16w..+16), k = feature
        bf16x8 a = *(const bf16x8*)(phi_lds + (16 * w + (l & 15)) * 272 + ks * 32 + (l >> 4) * 8);
        #pragma unroll
        for (int nt = 0; nt < 5; nt++) {
            bf16x8 b = *(const bf16x8*)(Zb + ((ks * 4 + (l >> 4)) * 80 + nt * 16 + (l & 15)) * 8);
            acc[nt] = __builtin_amdgcn_mfma_f32_16x16x32_bf16(a, b, acc[nt], 0, 0, 0);
        }
    }
    // denom = output column 64 -> tile 4, lanes with (l&15)==0; broadcast within 16-group
    float inv[4];
    #pragma unroll
    for (int reg = 0; reg < 4; reg++) {
        float den = __shfl(acc[4][reg], (l & 48));
        inv[reg] = 1.0f / den;
    }
    const int row = base + 16 * w + (l >> 4) * 4;
    #pragma unroll
    for (int nt = 0; nt < 4; nt++)
        #pragma unroll
        for (int reg = 0; reg < 4; reg++)
            out[(size_t)(row + reg) * 64 + nt * 16 + (l & 15)] = acc[nt][reg] * inv[reg];
}

extern "C" void kernel_launch(void* const* d_in, const int* in_sizes, int n_in,
                              void* d_out, int out_size, void* d_ws, size_t ws_size,
                              hipStream_t stream) {
    const float* q = (const float*)d_in[0];
    const float* k = (const float*)d_in[1];
    const float* v = (const float*)d_in[2];
    const float* P = (const float*)d_in[3];
    float* out = (float*)d_out;

    unsigned short* Pb = (unsigned short*)d_ws;            // 32 frags * 1KB = 32KB
    unsigned short* Zb = Pb + 32 * 512;                    // 20480 ushorts = 40KB
    float* partials = (float*)((char*)d_ws + 32768 + 40960);   // offset 73728

    long avail = ((long)ws_size - 73728) / (long)(PARTN * 4);
    int NB = 512;                                          // power of two so 65536/(64*NB) exact
    while (NB > 1 && (long)NB > avail) NB >>= 1;
    int chunks = 1024 / NB;

    prep_pb_kernel<<<1, 256, 0, stream>>>(P, Pb);
    kv_fused_kernel<<<NB, 256, 0, stream>>>(k, v, Pb, partials, chunks);
    reduce_kernel<<<80, 256, 0, stream>>>(partials, Zb, NB);
    q_out_kernel<<<1024, 256, 0, stream>>>(q, Pb, Zb, out);
}

// Round 4
// 141.316 us; speedup vs baseline: 8.0495x; 1.7488x over previous
//
#include <hip/hip_runtime.h>
#include <math.h>

typedef __attribute__((ext_vector_type(8))) short bf16x8;
typedef __attribute__((ext_vector_type(4))) float f32x4;

#define NROWS 65536
#define RFEAT 256
#define DDIM 64
#define NCOL 80                         // 64 v-cols + ksum col(64) + 15 pad
#define PARTN (RFEAT * NCOL)            // 20480 floats per partial slot
#define NGROUP 16                       // reduce stage-1 groups

// sc = 64^{-1/4} = 2^{-1.5}; ln(ratio) = ln(1/16)
#define SC 0.35355339059327373f
#define LNRATIO -2.772588722239781f

__device__ __forceinline__ unsigned short f2bf(float f) {
    union { float f; unsigned int u; } v; v.f = f;
    unsigned int r = v.u + 0x7FFFu + ((v.u >> 16) & 1u);   // RNE
    return (unsigned short)(r >> 16);
}

// ---------------- K0: P -> bf16 B-fragment layout (sc folded in) ----------------
// Pb holds 32 frags (kstep 0..1 x ntile 0..15); frag f, lane l at ushort idx f*512 + l*8.
// Frag element j = B[k][n] = sc*P[n][k], n = nt*16 + (l&15), k = kstep*32 + (l>>4)*8 + j.
__global__ void prep_pb_kernel(const float* __restrict__ P, unsigned short* __restrict__ Pb)
{
    const int t = threadIdx.x, l = t & 63, g = t >> 6;
    for (int f = g * 8; f < g * 8 + 8; f++) {
        const int kstep = f >> 4, nt = f & 15;
        const float* src = P + (nt * 16 + (l & 15)) * 64 + kstep * 32 + (l >> 4) * 8;
        bf16x8 frag;
        #pragma unroll
        for (int j = 0; j < 8; j++) frag[j] = (short)f2bf(SC * src[j]);
        *(bf16x8*)(Pb + f * 512 + l * 8) = frag;
    }
}

// ---------------- phi of a 64-row chunk -> LDS (bf16), via MFMA ----------------
// TRANS=true : phi_lds[col*LDP + row]  (A-frags along k-rows, for kv kernel)
// TRANS=false: phi_lds[row*LDP + col]  (A-frags along features, for q kernel)
template<int LDP, bool TRANS>
__device__ __forceinline__ void phi_chunk(const float* __restrict__ X, int chunkBase,
                                          const unsigned short* __restrict__ Pb,
                                          unsigned short* phi_lds, float* rc)
{
    const int t = threadIdx.x, l = t & 63, w = t >> 6;
    if (t < 64) {   // per-row constant: -0.5*sc^2*||x||^2 + ln(ratio)
        const float4* xr = (const float4*)(X + (size_t)(chunkBase + t) * 64);
        float s0 = 0.f, s1 = 0.f;
        #pragma unroll
        for (int j = 0; j < 16; j += 2) {
            float4 a = xr[j];     s0 += a.x*a.x + a.y*a.y + a.z*a.z + a.w*a.w;
            float4 b = xr[j + 1]; s1 += b.x*b.x + b.y*b.y + b.z*b.z + b.w*b.w;
        }
        rc[t] = -0.5f * (SC * SC) * (s0 + s1) + LNRATIO;
    }
    // A-frags: wave w owns rows [chunkBase+16w, +16); m = l&15, k = (l>>4)*8 + j (+32 for kstep 1)
    const float* ar = X + (size_t)(chunkBase + 16 * w + (l & 15)) * 64 + (l >> 4) * 8;
    bf16x8 a0, a1;
    #pragma unroll
    for (int j = 0; j < 8; j++) a0[j] = (short)f2bf(ar[j]);
    #pragma unroll
    for (int j = 0; j < 8; j++) a1[j] = (short)f2bf(ar[32 + j]);
    __syncthreads();   // rc ready; also: all threads finished reading previous chunk's phi_lds
    #pragma unroll
    for (int nt = 0; nt < 16; nt++) {
        bf16x8 b0 = *(const bf16x8*)(Pb + nt * 512 + l * 8);
        bf16x8 b1 = *(const bf16x8*)(Pb + (16 + nt) * 512 + l * 8);
        f32x4 acc = (f32x4){0.f, 0.f, 0.f, 0.f};
        acc = __builtin_amdgcn_mfma_f32_16x16x32_bf16(a0, b0, acc, 0, 0, 0);
        acc = __builtin_amdgcn_mfma_f32_16x16x32_bf16(a1, b1, acc, 0, 0, 0);
        const int col = nt * 16 + (l & 15);
        #pragma unroll
        for (int reg = 0; reg < 4; reg++) {
            const int rloc = 16 * w + (l >> 4) * 4 + reg;   // D: row=(l>>4)*4+reg, col=l&15
            float phi = __expf(acc[reg] + rc[rloc]);
            if (TRANS) phi_lds[col * LDP + rloc] = f2bf(phi);
            else       phi_lds[rloc * LDP + col] = f2bf(phi);
        }
    }
    __syncthreads();
}

// ---------------- kv_fused: partials = phi(K)^T @ [V | 1] over this block's rows ----------------
__global__ __launch_bounds__(256, 2)
void kv_fused_kernel(const float* __restrict__ Kp, const float* __restrict__ V,
                     const unsigned short* __restrict__ Pb,
                     float* __restrict__ partials, int chunksPerBlock)
{
    __shared__ unsigned short phi_lds[RFEAT * 72];   // [feat][krow], padded
    __shared__ float rc[64];
    const int t = threadIdx.x, l = t & 63, w = t >> 6;

    f32x4 acc[4][5];
    #pragma unroll
    for (int mt = 0; mt < 4; mt++)
        #pragma unroll
        for (int nt = 0; nt < 5; nt++) acc[mt][nt] = (f32x4){0.f, 0.f, 0.f, 0.f};

    bf16x8 ones;   // B-frag for ksum column: B[k][64]=1, rest 0 -> lanes with (l&15)==0
    #pragma unroll
    for (int j = 0; j < 8; j++) ones[j] = (short)(((l & 15) == 0) ? 0x3F80 : 0);

    const int base = blockIdx.x * chunksPerBlock * 64;
    for (int c = 0; c < chunksPerBlock; c++) {
        const int cb = base + c * 64;
        phi_chunk<72, true>(Kp, cb, Pb, phi_lds, rc);
        #pragma unroll
        for (int ks = 0; ks < 2; ks++) {
            bf16x8 af[4];   // A = phi(K)^T: m=feature, k=krow; wave w owns feats [64w,+64)
            #pragma unroll
            for (int mt = 0; mt < 4; mt++)
                af[mt] = *(const bf16x8*)(phi_lds + (64 * w + mt * 16 + (l & 15)) * 72
                                          + ks * 32 + (l >> 4) * 8);
            const int krow = cb + ks * 32 + (l >> 4) * 8;
            bf16x8 bf4[4];  // B = V[k][n]: n = nt*16 + (l&15), k along j (row-strided)
            #pragma unroll
            for (int nt = 0; nt < 4; nt++) {
                const float* vp = V + (size_t)krow * 64 + nt * 16 + (l & 15);
                bf16x8 bb;
                #pragma unroll
                for (int j = 0; j < 8; j++) bb[j] = (short)f2bf(vp[j * 64]);
                bf4[nt] = bb;
            }
            #pragma unroll
            for (int mt = 0; mt < 4; mt++) {
                #pragma unroll
                for (int nt = 0; nt < 4; nt++)
                    acc[mt][nt] = __builtin_amdgcn_mfma_f32_16x16x32_bf16(af[mt], bf4[nt], acc[mt][nt], 0, 0, 0);
                acc[mt][4] = __builtin_amdgcn_mfma_f32_16x16x32_bf16(af[mt], ones, acc[mt][4], 0, 0, 0);
            }
        }
    }
    float* slot = partials + (size_t)blockIdx.x * PARTN;
    #pragma unroll
    for (int mt = 0; mt < 4; mt++)
        #pragma unroll
        for (int nt = 0; nt < 5; nt++)
            #pragma unroll
            for (int reg = 0; reg < 4; reg++)
                slot[(64 * w + mt * 16 + (l >> 4) * 4 + reg) * 80 + nt * 16 + (l & 15)] = acc[mt][nt][reg];
}

// ---------------- reduce stage 1: sum a group of slots -> p2[g][20480] ----------------
__global__ __launch_bounds__(256)
void reduce1_kernel(const float* __restrict__ partials, float* __restrict__ p2,
                    int slotsPerGroup)
{
    const int idx = blockIdx.x * 256 + threadIdx.x;   // 80*256 == 20480 exactly
    const int g = blockIdx.y;
    const float* base = partials + (size_t)g * slotsPerGroup * PARTN + idx;
    float s0 = 0.f, s1 = 0.f, s2 = 0.f, s3 = 0.f;
    int b = 0;
    for (; b + 4 <= slotsPerGroup; b += 4) {
        s0 += base[(size_t)(b + 0) * PARTN];
        s1 += base[(size_t)(b + 1) * PARTN];
        s2 += base[(size_t)(b + 2) * PARTN];
        s3 += base[(size_t)(b + 3) * PARTN];
    }
    for (; b < slotsPerGroup; b++) s0 += base[(size_t)b * PARTN];
    p2[(size_t)g * PARTN + idx] = (s0 + s1) + (s2 + s3);
}

// ---------------- reduce stage 2: sum groups -> Zb (bf16, B-frag octet layout) ----------------
// Zb element (m,n) at ushort ((m>>3)*80 + n)*8 + (m&7); col 64 = ksum.
__global__ __launch_bounds__(256)
void reduce2_kernel(const float* __restrict__ p2, unsigned short* __restrict__ Zb, int ngroups)
{
    const int idx = blockIdx.x * 256 + threadIdx.x;
    float s = 0.f;
    for (int g = 0; g < ngroups; g++) s += p2[(size_t)g * PARTN + idx];
    const int m = idx / 80, n = idx - m * 80;
    Zb[((m >> 3) * 80 + n) * 8 + (m & 7)] = f2bf(s);
}

// ---------------- q_out: out = normalize( phi(Q) @ Zb ) ----------------
__global__ __launch_bounds__(256, 2)
void q_out_kernel(const float* __restrict__ Q, const unsigned short* __restrict__ Pb,
                  const unsigned short* __restrict__ Zb, float* __restrict__ out)
{
    __shared__ unsigned short phi_lds[64 * 272];   // [row][feat], padded (544B rows, 16B-aligned)
    __shared__ float rc[64];
    const int t = threadIdx.x, l = t & 63, w = t >> 6;
    const int base = blockIdx.x * 64;

    phi_chunk<272, false>(Q, base, Pb, phi_lds, rc);

    f32x4 acc[5];
    #pragma unroll
    for (int nt = 0; nt < 5; nt++) acc[nt] = (f32x4){0.f, 0.f, 0.f, 0.f};

    #pragma unroll
    for (int ks = 0; ks < 8; ks++) {
        // A = phi(Q): m = qrow (wave w rows 16w..+16), k = feature
        bf16x8 a = *(const bf16x8*)(phi_lds + (16 * w + (l & 15)) * 272 + ks * 32 + (l >> 4) * 8);
        #pragma unroll
        for (int nt = 0; nt < 5; nt++) {
            bf16x8 b = *(const bf16x8*)(Zb + ((ks * 4 + (l >> 4)) * 80 + nt * 16 + (l & 15)) * 8);
            acc[nt] = __builtin_amdgcn_mfma_f32_16x16x32_bf16(a, b, acc[nt], 0, 0, 0);
        }
    }
    // denom = output column 64 -> tile 4, lanes with (l&15)==0; broadcast within 16-group
    float inv[4];
    #pragma unroll
    for (int reg = 0; reg < 4; reg++) {
        float den = __shfl(acc[4][reg], (l & 48));
        inv[reg] = 1.0f / den;
    }
    const int row = base + 16 * w + (l >> 4) * 4;
    #pragma unroll
    for (int nt = 0; nt < 4; nt++)
        #pragma unroll
        for (int reg = 0; reg < 4; reg++)
            out[(size_t)(row + reg) * 64 + nt * 16 + (l & 15)] = acc[nt][reg] * inv[reg];
}

extern "C" void kernel_launch(void* const* d_in, const int* in_sizes, int n_in,
                              void* d_out, int out_size, void* d_ws, size_t ws_size,
                              hipStream_t stream) {
    const float* q = (const float*)d_in[0];
    const float* k = (const float*)d_in[1];
    const float* v = (const float*)d_in[2];
    const float* P = (const float*)d_in[3];
    float* out = (float*)d_out;

    unsigned short* Pb = (unsigned short*)d_ws;                  // 32 frags * 1KB = 32KB
    unsigned short* Zb = Pb + 32 * 512;                          // 20480 ushorts = 40KB
    float* p2 = (float*)((char*)d_ws + 32768 + 40960);           // NGROUP*PARTN*4 = 1.3MB
    float* partials = p2 + (size_t)NGROUP * PARTN;               // NB*PARTN*4

    long fixedBytes = 32768 + 40960 + (long)NGROUP * PARTN * 4;
    long avail = ((long)ws_size - fixedBytes) / (long)(PARTN * 4);
    int NB = 512;                                                // power of two; 65536/(64*NB) exact
    while (NB > NGROUP && (long)NB > avail) NB >>= 1;
    int chunks = 1024 / NB;
    int ngroups = (NB >= NGROUP) ? NGROUP : NB;
    int spg = NB / ngroups;

    prep_pb_kernel<<<1, 256, 0, stream>>>(P, Pb);
    kv_fused_kernel<<<NB, 256, 0, stream>>>(k, v, Pb, partials, chunks);
    reduce1_kernel<<<dim3(80, ngroups), 256, 0, stream>>>(partials, p2, spg);
    reduce2_kernel<<<80, 256, 0, stream>>>(p2, Zb, ngroups);
    q_out_kernel<<<1024, 256, 0, stream>>>(q, Pb, Zb, out);
}